// Round 2
// 260.053 us; speedup vs baseline: 1.0594x; 1.0594x over previous
//
#include <hip/hip_runtime.h>
#include <hip/hip_fp16.h>
#include <math.h>

#define N_NODES 100000
#define N_EDGES 3200000
#define IN_DIM 11
#define HID 32
#define HID2 16
#define SCHUNK 100352   // per-array stride in ws (multiple of 128)
#define BINSHIFT 8
#define BINSZ 256
#define NB 391          // ceil(100000/256)
#define CHUNK 8192      // edges per block in hist/scatter (391 blocks)

// ---------------- binned CSR build (exact counts; prefix computed in-block) ----------------
__global__ __launch_bounds__(1024) void k_hist(const int* __restrict__ ei,
                                               int* __restrict__ bincnt) {
    __shared__ int h[NB];
    for (int i = threadIdx.x; i < NB; i += 1024) h[i] = 0;
    __syncthreads();
    int b0 = blockIdx.x * CHUNK;
    int e1 = b0 + CHUNK; if (e1 > N_EDGES) e1 = N_EDGES;
    for (int e = b0 + threadIdx.x; e < e1; e += 1024)
        atomicAdd(&h[ei[N_EDGES + e] >> BINSHIFT], 1);
    __syncthreads();
    for (int i = threadIdx.x; i < NB; i += 1024)
        if (h[i]) atomicAdd(&bincnt[i], h[i]);
}

__global__ __launch_bounds__(1024) void k_binscatter(const int* __restrict__ ei,
                                                     const int* __restrict__ bincnt,
                                                     int* __restrict__ bincur,
                                                     unsigned* __restrict__ binbuf) {
    __shared__ int pre[NB];
    __shared__ int h[NB];
    __shared__ int base[NB];
    __shared__ int tmp[512];
    int tid = threadIdx.x;
    int v = (tid < NB) ? bincnt[tid] : 0;
    if (tid < 512) tmp[tid] = v;
    __syncthreads();
    for (int off = 1; off < 512; off <<= 1) {
        int t = (tid < 512 && tid >= off) ? tmp[tid - off] : 0;
        __syncthreads();
        if (tid < 512) tmp[tid] += t;
        __syncthreads();
    }
    if (tid < NB) pre[tid] = tmp[tid] - v;
    for (int i = tid; i < NB; i += 1024) h[i] = 0;
    __syncthreads();
    int b0 = blockIdx.x * CHUNK;
    int e1 = b0 + CHUNK; if (e1 > N_EDGES) e1 = N_EDGES;
    for (int e = b0 + tid; e < e1; e += 1024)
        atomicAdd(&h[ei[N_EDGES + e] >> BINSHIFT], 1);
    __syncthreads();
    for (int i = tid; i < NB; i += 1024) {
        int c = h[i];
        if (c) base[i] = pre[i] + atomicAdd(&bincur[i], c);
        h[i] = 0;
    }
    __syncthreads();
    for (int e = b0 + tid; e < e1; e += 1024) {
        int d = ei[N_EDGES + e];
        int s = ei[e];
        int b = d >> BINSHIFT;
        int p = base[b] + atomicAdd(&h[b], 1);
        binbuf[p] = (unsigned)s | ((unsigned)(d & (BINSZ - 1)) << 17);  // s < 2^17
    }
}

__global__ __launch_bounds__(1024) void k_binfill(const unsigned* __restrict__ binbuf,
                                                  const int* __restrict__ bincnt,
                                                  int* __restrict__ rowstart,
                                                  float* __restrict__ dinv,
                                                  int* __restrict__ csr_src) {
    int b = blockIdx.x;
    int tid = threadIdx.x;
    __shared__ int tmp[512];
    __shared__ int cnt[BINSZ];
    __shared__ int rloc[BINSZ];
    __shared__ int cur[BINSZ];
    int v = (tid < 512 && tid < b) ? bincnt[tid] : 0;
    if (tid < 512) tmp[tid] = v;
    __syncthreads();
    for (int off = 256; off >= 1; off >>= 1) {
        if (tid < off) tmp[tid] += tmp[tid + off];
        __syncthreads();
    }
    int ebeg = tmp[0];
    int eend = ebeg + bincnt[b];
    __syncthreads();
    if (tid < BINSZ) cnt[tid] = 0;
    __syncthreads();
    for (int e = ebeg + tid; e < eend; e += 1024)
        atomicAdd(&cnt[binbuf[e] >> 17], 1);
    __syncthreads();
    int c = (tid < BINSZ) ? cnt[tid] : 0;
    if (tid < BINSZ) tmp[tid] = c;
    __syncthreads();
    for (int off = 1; off < BINSZ; off <<= 1) {
        int t = (tid < BINSZ && tid >= off) ? tmp[tid - off] : 0;
        __syncthreads();
        if (tid < BINSZ) tmp[tid] += t;
        __syncthreads();
    }
    if (tid < BINSZ) {
        rloc[tid] = tmp[tid] - c;
        cur[tid] = 0;
        int node = b * BINSZ + tid;
        if (node < N_NODES) {
            rowstart[node] = ebeg + rloc[tid];
            dinv[node] = rsqrtf((float)c + 1.0f);  // +1 self-loop
        }
    }
    if (b == 0 && tid == 0) rowstart[N_NODES] = N_EDGES;  // sentinel
    __syncthreads();
    for (int e = ebeg + tid; e < eend; e += 1024) {
        unsigned vv = binbuf[e];
        int dl = vv >> 17;
        int s = (int)(vv & 0x1FFFFu);
        int p = ebeg + rloc[dl] + atomicAdd(&cur[dl], 1);
        csr_src[p] = s;
    }
}

// ---------------- dense transform 1 (write dinv-scaled fp16, interleaved [node*32+j]) -----
__global__ void k_xw1(const float* __restrict__ x, const float* __restrict__ W1,
                      const float* __restrict__ dinv, __half* __restrict__ xwh) {
    int t = blockIdx.x * blockDim.x + threadIdx.x;
    int node = t >> 5;
    int j = t & 31;
    __shared__ float sW[IN_DIM * HID];
    __shared__ float sx[8 * IN_DIM];
    for (int i = threadIdx.x; i < IN_DIM * HID; i += 256) sW[i] = W1[i];
    int base = blockIdx.x * 8;
    if (threadIdx.x < 8 * IN_DIM) sx[threadIdx.x] = x[base * IN_DIM + threadIdx.x];
    __syncthreads();
    int ln = node - base;
    float acc = 0.0f;
#pragma unroll
    for (int k = 0; k < IN_DIM; ++k)
        acc += sx[ln * IN_DIM + k] * sW[k * HID + j];
    xwh[t] = __float2half(dinv[node] * acc);
}

// ---------------- wide edge gather ----------------
// Octet decomposition: within a 32-lane group (one node), lane l handles
// edge (e + (l>>2)) and feature octet oj = (l&3)*8 .. +7, loading 16 B per
// edge (dwordx4 of 8 halves).  8 edges per group per load instruction vs 1
// before -> 8x fewer load instrs, ~2.5x fewer VALU.  Per-j partial sums sit
// in acc[8] (compile-time indexed), reduced across the 8 lanes sharing an
// octet (xor 4/8/16) at the end.
__device__ __forceinline__ void accum8(float* __restrict__ acc, const uint4 v) {
    float2 f0 = __half22float2(*(const __half2*)&v.x);
    float2 f1 = __half22float2(*(const __half2*)&v.y);
    float2 f2 = __half22float2(*(const __half2*)&v.z);
    float2 f3 = __half22float2(*(const __half2*)&v.w);
    acc[0] += f0.x; acc[1] += f0.y;
    acc[2] += f1.x; acc[3] += f1.y;
    acc[4] += f2.x; acc[5] += f2.y;
    acc[6] += f3.x; acc[7] += f3.y;
}

__device__ __forceinline__ void edge_accum8(int beg, int end, int q, int oj,
                                            const int* __restrict__ csr_src,
                                            const __half* __restrict__ xwh,
                                            float* __restrict__ acc) {
#pragma unroll
    for (int k = 0; k < 8; ++k) acc[k] = 0.0f;
    int e = beg;
    // 32 edges / iteration: 4 independent index loads + 4 dwordx4 in flight
    for (; e + 32 <= end; e += 32) {
        int s0 = csr_src[e + q];
        int s1 = csr_src[e + 8 + q];
        int s2 = csr_src[e + 16 + q];
        int s3 = csr_src[e + 24 + q];
        uint4 v0 = *(const uint4*)(xwh + ((s0 << 5) | oj));
        uint4 v1 = *(const uint4*)(xwh + ((s1 << 5) | oj));
        uint4 v2 = *(const uint4*)(xwh + ((s2 << 5) | oj));
        uint4 v3 = *(const uint4*)(xwh + ((s3 << 5) | oj));
        accum8(acc, v0); accum8(acc, v1); accum8(acc, v2); accum8(acc, v3);
    }
    if (e + 16 <= end) {
        int s0 = csr_src[e + q];
        int s1 = csr_src[e + 8 + q];
        uint4 v0 = *(const uint4*)(xwh + ((s0 << 5) | oj));
        uint4 v1 = *(const uint4*)(xwh + ((s1 << 5) | oj));
        accum8(acc, v0); accum8(acc, v1);
        e += 16;
    }
    if (e + 8 <= end) {
        int s0 = csr_src[e + q];
        uint4 v0 = *(const uint4*)(xwh + ((s0 << 5) | oj));
        accum8(acc, v0);
        e += 8;
    }
    if (e + q < end) {  // masked tail: lanes with q < remaining participate
        int s0 = csr_src[e + q];
        uint4 v0 = *(const uint4*)(xwh + ((s0 << 5) | oj));
        accum8(acc, v0);
    }
    // reduce over the 8 lanes (stride 4) sharing this j-octet
#pragma unroll
    for (int m = 4; m <= 16; m <<= 1) {
#pragma unroll
        for (int k = 0; k < 8; ++k) acc[k] += __shfl_xor(acc[k], m);
    }
}

// ---------------- layer-1 gather fused with bias1+relu and the W2 transform ---------------
// grid exactly N_NODES/8 blocks (no early returns -> barriers safe)
__global__ __launch_bounds__(256) void k_gather_xw2(const int* __restrict__ rowstart,
                                                    const float* __restrict__ dinv,
                                                    const int* __restrict__ csr_src,
                                                    const __half* __restrict__ xwh1,
                                                    const float* __restrict__ b1,
                                                    const float* __restrict__ W2,
                                                    __half* __restrict__ xwh2) {
    __shared__ float sW2[HID * HID];
    __shared__ float sA[8][33];   // raw gather sums (j-indexed)
    __shared__ float sH[8][33];   // relu'd hidden
    for (int i = threadIdx.x; i < HID * HID; i += 256) sW2[i] = W2[i];

    int ln = threadIdx.x >> 5;
    int node = blockIdx.x * 8 + ln;
    int l = threadIdx.x & 31;
    int q = l >> 2;
    int oj = (l & 3) << 3;

    float acc[8];
    edge_accum8(rowstart[node], rowstart[node + 1], q, oj, csr_src, xwh1, acc);
    if (q == 0) {
#pragma unroll
        for (int k = 0; k < 8; ++k) sA[ln][oj + k] = acc[k];
    }
    __syncthreads();  // covers sW2 staging + sA writes

    int j = l;
    float dd = dinv[node];
    float hv = dd * (sA[ln][j] + __half2float(xwh1[node * HID + j])) + b1[j];
    sH[ln][j] = hv > 0.0f ? hv : 0.0f;  // H = relu(agg + b1)
    __syncthreads();

    // XWH2[node][j] = fp16( dinv[node] * sum_k H[k] * W2[k][j] )
    float a2 = 0.0f;
#pragma unroll
    for (int k = 0; k < HID; ++k) a2 += sH[ln][k] * sW2[k * HID + j];
    xwh2[node * HID + j] = __float2half(dd * a2);
}

// ---------------- layer-2 gather fused with bias2+relu and the output MLP ----------------
__global__ __launch_bounds__(256) void k_gather_mlp(const int* __restrict__ rowstart,
                                                    const float* __restrict__ dinv,
                                                    const int* __restrict__ csr_src,
                                                    const __half* __restrict__ xwh,
                                                    const float* __restrict__ b2,
                                                    const float* __restrict__ Wo1,
                                                    const float* __restrict__ bo1,
                                                    const float* __restrict__ Wo2,
                                                    const float* __restrict__ bo2,
                                                    float* __restrict__ out) {
    __shared__ float sW1[HID * HID2];
    __shared__ float sb1[HID2];
    __shared__ float sW2v[HID2];
    __shared__ float sb2[HID];
    __shared__ float sA[8][33];
    __shared__ float sH[8][33];
    for (int i = threadIdx.x; i < HID * HID2; i += 256) sW1[i] = Wo1[i];
    if (threadIdx.x < HID2) {
        sb1[threadIdx.x] = bo1[threadIdx.x];
        sW2v[threadIdx.x] = Wo2[threadIdx.x];
    }
    if (threadIdx.x < HID) sb2[threadIdx.x] = b2[threadIdx.x];

    int ln = threadIdx.x >> 5;
    int node = blockIdx.x * 8 + ln;
    int l = threadIdx.x & 31;
    int q = l >> 2;
    int oj = (l & 3) << 3;

    float acc[8];
    edge_accum8(rowstart[node], rowstart[node + 1], q, oj, csr_src, xwh, acc);
    if (q == 0) {
#pragma unroll
        for (int k = 0; k < 8; ++k) sA[ln][oj + k] = acc[k];
    }
    __syncthreads();  // covers weight staging + sA writes

    int j = l;
    float dd = dinv[node];
    float hv = dd * (sA[ln][j] + __half2float(xwh[node * HID + j])) + sb2[j];
    sH[ln][j] = hv > 0.0f ? hv : 0.0f;  // relu(agg + b2)
    __syncthreads();

    float val = 0.0f;
    if (j < HID2) {
        float a = sb1[j];
#pragma unroll
        for (int k = 0; k < HID; ++k) a += sH[ln][k] * sW1[k * HID2 + j];
        a = a > 0.0f ? a : (expf(a) - 1.0f);  // elu alpha=1
        val = a * sW2v[j];
    }
#pragma unroll
    for (int d = 16; d >= 1; d >>= 1) val += __shfl_down(val, d, 32);
    if (j == 0) out[node] = val + bo2[0];
}

extern "C" void kernel_launch(void* const* d_in, const int* in_sizes, int n_in,
                              void* d_out, int out_size, void* d_ws, size_t ws_size,
                              hipStream_t stream) {
    const float* x   = (const float*)d_in[0];
    const int*   ei  = (const int*)d_in[1];
    const float* W1  = (const float*)d_in[3];
    const float* b1  = (const float*)d_in[4];
    const float* W2  = (const float*)d_in[5];
    const float* b2  = (const float*)d_in[6];
    const float* Wo1 = (const float*)d_in[7];
    const float* bo1 = (const float*)d_in[8];
    const float* Wo2 = (const float*)d_in[9];
    const float* bo2 = (const float*)d_in[10];
    float* out = (float*)d_out;

    // ws layout (4B units):
    // bincnt[512] | bincur[512] | rowstart[SCHUNK] | dinv[SCHUNK]
    // | csr_src[E] | binbuf[E] | XWH1[N*HID fp16] | XWH2[N*HID fp16]
    int*      bincnt   = (int*)d_ws;
    int*      bincur   = bincnt + 512;
    int*      rowstart = bincur + 512;
    float*    dinv     = (float*)(rowstart + SCHUNK);
    int*      csr_src  = (int*)(dinv + SCHUNK);
    unsigned* binbuf   = (unsigned*)(csr_src + N_EDGES);
    __half*   XWH1     = (__half*)(binbuf + N_EDGES);
    __half*   XWH2     = XWH1 + (size_t)N_NODES * HID;

    const int BT = 256;
    int gNH  = (N_NODES * HID + BT - 1) / BT;       // 12500
    int gC   = (N_EDGES + CHUNK - 1) / CHUNK;       // 391
    int gG   = N_NODES / 8;                         // 12500 (exact)

    // binned CSR build (rowstart, dinv, csr_src)
    hipMemsetAsync(bincnt, 0, 1024 * sizeof(int), stream);  // bincnt + bincur
    k_hist      <<<gC, 1024, 0, stream>>>(ei, bincnt);
    k_binscatter<<<gC, 1024, 0, stream>>>(ei, bincnt, bincur, binbuf);
    k_binfill   <<<NB, 1024, 0, stream>>>(binbuf, bincnt, rowstart, dinv, csr_src);

    // layer 1 (+ fused W2): XWH1 = fp16(dinv.*(x@W1)); XWH2 = fp16(dinv.*(relu(gather+b1)@W2))
    k_xw1<<<gNH, BT, 0, stream>>>(x, W1, dinv, XWH1);
    k_gather_xw2<<<gG, BT, 0, stream>>>(rowstart, dinv, csr_src, XWH1, b1, W2, XWH2);

    // layer 2 + head: out = MLP(relu(dinv.*gather(XWH2) + b2))
    k_gather_mlp<<<gG, BT, 0, stream>>>(rowstart, dinv, csr_src, XWH2,
                                        b2, Wo1, bo1, Wo2, bo2, out);
}